// Round 5
// baseline (723.834 us; speedup 1.0000x reference)
//
#include <hip/hip_runtime.h>
#include <math.h>

#define LSZ 128
#define NCH 8
#define NLAY 16
#define NT 576          // 9 waves
#define NACT 528        // active tiles: 4x4 blocks with g>=s

__device__ __forceinline__ float4 f4add(float4 a, float4 b) {
    return make_float4(a.x + b.x, a.y + b.y, a.z + b.z, a.w + b.w);
}
__device__ __forceinline__ float4 f4fma(float s, float4 a, float4 acc) {
    return make_float4(fmaf(s, a.x, acc.x), fmaf(s, a.y, acc.y),
                       fmaf(s, a.z, acc.z), fmaf(s, a.w, acc.w));
}
__device__ __forceinline__ float4 f4scale(float s, float4 a) {
    return make_float4(s * a.x, s * a.y, s * a.z, s * a.w);
}
// CELU(y) = max(y,0) + exp(min(y,0)) - 1 ; exact for y>=0.
__device__ __forceinline__ float celu1(float y) {
    return fmaxf(y, 0.f) + (__expf(fminf(y, 0.f)) - 1.f);
}
__device__ __forceinline__ float uni(float v) {
    return __uint_as_float(__builtin_amdgcn_readfirstlane(__float_as_uint(v)));
}
// compile-time component select (k constant after unroll -> folds, no scratch)
__device__ __forceinline__ float f4c(float4 v, int k) {
    return k == 0 ? v.x : k == 1 ? v.y : k == 2 ? v.z : v.w;
}

// Symmetric-plane kernel: plane x stays symmetric through every layer
// (symmetric init; cross stencil commutes with transpose exactly: h/v pairs
// swap and float add is commutative). Only 4x4 blocks with block-col >=
// block-row (528 of 1024) are computed & stored; reads into the lower
// region are redirected to the transposed stored block. Reduction counts
// strictly-upper tiles twice. Values are bit-identical to the full plane.
__global__ __launch_bounds__(NT, 5)
void plane_kernel(const float* __restrict__ nrm,   // (256,128,3)
                  const float* __restrict__ W,     // (16,8,5)
                  float* __restrict__ ws)          // (2048,) per-block sums
{
    __shared__ float x[LSZ * LSZ];     // 65536 B (upper blocks valid)
    __shared__ float nsm[LSZ * 3];
    __shared__ float wsm[NLAY * 5];
    __shared__ float red[NT / 64];

    const int bid = blockIdx.x;
    const int b   = bid >> 3;
    const int c   = bid & 7;
    const int tid = threadIdx.x;

    if (tid < LSZ * 3) nsm[tid] = nrm[b * (LSZ * 3) + tid];
    if (tid < NLAY * 5) {
        int l = tid / 5, d = tid % 5;
        wsm[tid] = W[l * (NCH * 5) + c * 5 + d];
    }

    const bool active = tid < NACT;
    int s = 0, g = 0;
    if (active) {
        int rem = tid;
#pragma unroll 1
        while (rem >= 32 - s) { rem -= 32 - s; ++s; }   // strip s has 32-s tiles
        g = s + rem;
    }
    const int i0 = 4 * s, j0 = 4 * g;
    const bool diag = (g == s);
    const int sT = (s + 31) & 31, sB = (s + 1) & 31;
    const int gL = (g + 31) & 31, gR = (g + 1) & 31;
    const bool Tst = (g >= sT);   // false only for s==0 && g<31 (wrap)
    const bool Bst = (g >= sB);   // false only for diag && s<31
    const bool Lst = (gL >= s);   // false only for diag && s>=1
    const bool Rst = (gR >= s);   // false only for g==31 && s>=1 (wrap)

    float4 own[4];                 // this tile's 4 rows (carried across layers)

    __syncthreads();               // nsm/wsm ready

    // ---- init: own block of g = n n^T, zero diagonal ----
    if (active) {
        float njx[4], njy[4], njz[4];
#pragma unroll
        for (int q = 0; q < 4; ++q) {
            njx[q] = nsm[(j0 + q) * 3 + 0];
            njy[q] = nsm[(j0 + q) * 3 + 1];
            njz[q] = nsm[(j0 + q) * 3 + 2];
        }
#pragma unroll
        for (int k = 0; k < 4; ++k) {
            int r = i0 + k;
            float n0 = nsm[r * 3 + 0], n1 = nsm[r * 3 + 1], n2 = nsm[r * 3 + 2];
            own[k] = make_float4(n0 * njx[0] + n1 * njy[0] + n2 * njz[0],
                                 n0 * njx[1] + n1 * njy[1] + n2 * njz[1],
                                 n0 * njx[2] + n1 * njy[2] + n2 * njz[2],
                                 n0 * njx[3] + n1 * njy[3] + n2 * njz[3]);
        }
        if (diag) { own[0].x = 0.f; own[1].y = 0.f; own[2].z = 0.f; own[3].w = 0.f; }
#pragma unroll
        for (int k = 0; k < 4; ++k)
            *(float4*)&x[(i0 + k) * LSZ + j0] = own[k];
    }
    __syncthreads();

#pragma unroll 1
    for (int l = 0; l < NLAY; ++l) {
        const float w0 = uni(wsm[l * 5 + 0]);
        const float w1 = uni(wsm[l * 5 + 1]);
        const float w2 = uni(wsm[l * 5 + 2]);
        const float w3 = uni(wsm[l * 5 + 3]);
        const float w4 = uni(wsm[l * 5 + 4]);

        float4 blkT[4], blkB[4], res[4];
        if (active) {
            // --- top halo block (rows i0-4..i0-1, cols j0..j0+3) ---
            if (Tst) {
#pragma unroll
                for (int k = 0; k < 4; ++k)
                    blkT[k] = *(const float4*)&x[(4 * sT + k) * LSZ + j0];
            } else {  // partner block (g,31): rows 4g+c, cols 124..127
                float4 t0 = *(const float4*)&x[(4 * g + 0) * LSZ + 4 * sT];
                float4 t1 = *(const float4*)&x[(4 * g + 1) * LSZ + 4 * sT];
                float4 t2 = *(const float4*)&x[(4 * g + 2) * LSZ + 4 * sT];
                float4 t3 = *(const float4*)&x[(4 * g + 3) * LSZ + 4 * sT];
#pragma unroll
                for (int k = 0; k < 4; ++k)
                    blkT[k] = make_float4(f4c(t0, k), f4c(t1, k), f4c(t2, k), f4c(t3, k));
            }
            // --- bottom halo block (rows i0+4..i0+7, cols j0..j0+3) ---
            if (Bst) {
#pragma unroll
                for (int k = 0; k < 4; ++k)
                    blkB[k] = *(const float4*)&x[(4 * sB + k) * LSZ + j0];
            } else {  // diag: partner block (s, s+1) = R-block location
                float4 t0 = *(const float4*)&x[(4 * g + 0) * LSZ + 4 * sB];
                float4 t1 = *(const float4*)&x[(4 * g + 1) * LSZ + 4 * sB];
                float4 t2 = *(const float4*)&x[(4 * g + 2) * LSZ + 4 * sB];
                float4 t3 = *(const float4*)&x[(4 * g + 3) * LSZ + 4 * sB];
#pragma unroll
                for (int k = 0; k < 4; ++k)
                    blkB[k] = make_float4(f4c(t0, k), f4c(t1, k), f4c(t2, k), f4c(t3, k));
            }

            // vertical stack: V(k) k=0..11 = rows i0-4 .. i0+7
#define VV(k) ((k) < 4 ? blkT[(k)] : (k) < 8 ? own[(k) - 4] : blkB[(k) - 8])

#pragma unroll
            for (int a = 0; a < 4; ++a) {
                float4 Lr, Rr;
                if (Lst) Lr = *(const float4*)&x[(i0 + a) * LSZ + 4 * gL];
                else     Lr = make_float4(f4c(blkT[0], a), f4c(blkT[1], a),
                                          f4c(blkT[2], a), f4c(blkT[3], a));
                if (Rst) Rr = *(const float4*)&x[(i0 + a) * LSZ + 4 * gR];
                else     Rr = make_float4(x[0 * LSZ + i0 + a], x[1 * LSZ + i0 + a],
                                          x[2 * LSZ + i0 + a], x[3 * LSZ + i0 + a]);
                const float4 C = own[a];

                float4 h1 = make_float4(Lr.w + C.y, C.x + C.z, C.y + C.w, C.z + Rr.x);
                float4 h2 = make_float4(Lr.z + C.z, Lr.w + C.w, C.x + Rr.x, C.y + Rr.y);
                float4 h3 = make_float4(Lr.y + C.w, Lr.z + Rr.x, Lr.w + Rr.y, C.x + Rr.z);
                float4 h4 = f4add(Lr, Rr);

                float4 y = f4scale(w0, C);
                y = f4fma(w1, f4add(h1, f4add(VV(a + 3), VV(a + 5))), y);
                y = f4fma(w2, f4add(h2, f4add(VV(a + 2), VV(a + 6))), y);
                y = f4fma(w3, f4add(h3, f4add(VV(a + 1), VV(a + 7))), y);
                y = f4fma(w4, f4add(h4, f4add(VV(a + 0), VV(a + 8))), y);

                res[a].x = C.x + celu1(y.x);
                res[a].y = C.y + celu1(y.y);
                res[a].z = C.z + celu1(y.z);
                res[a].w = C.w + celu1(y.w);
            }
#undef VV
        }
        __syncthreads();
        if (active) {
#pragma unroll
            for (int k = 0; k < 4; ++k) {
                *(float4*)&x[(i0 + k) * LSZ + j0] = res[k];
                own[k] = res[k];
            }
        }
        __syncthreads();
    }

    // ---- reduction: upper tiles count twice (mirror), diag once ----
    float local = 0.f;
    if (active) {
#pragma unroll
        for (int k = 0; k < 4; ++k)
            local += own[k].x + own[k].y + own[k].z + own[k].w;
        if (!diag) local += local;
    }
#pragma unroll
    for (int off = 32; off > 0; off >>= 1)
        local += __shfl_down(local, off, 64);

    const int wave = tid >> 6;
    if ((tid & 63) == 0) red[wave] = local;
    __syncthreads();
    if (tid == 0) {
        float ssum = 0.f;
#pragma unroll
        for (int w = 0; w < NT / 64; ++w) ssum += red[w];
        ws[bid] = ssum;
    }
}

__global__ void finish_kernel(const float* __restrict__ ws, float* __restrict__ out) {
    int b = threadIdx.x;
    float s = 0.f;
#pragma unroll
    for (int c = 0; c < NCH; ++c) s += ws[b * NCH + c];
    out[b] = expf(-s / (8.0f * 128.0f * 128.0f));
}

extern "C" void kernel_launch(void* const* d_in, const int* in_sizes, int n_in,
                              void* d_out, int out_size, void* d_ws, size_t ws_size,
                              hipStream_t stream) {
    const float* nrm = (const float*)d_in[0];   // (256,128,3) f32
    const float* W   = (const float*)d_in[1];   // (16,8,5) f32
    float* out = (float*)d_out;                 // (256,) f32
    float* ws  = (float*)d_ws;                  // >= 2048 f32 scratch

    plane_kernel<<<dim3(256 * NCH), dim3(NT), 0, stream>>>(nrm, W, ws);
    finish_kernel<<<dim3(1), dim3(256), 0, stream>>>(ws, out);
}

// Round 6
// 492.811 us; speedup vs baseline: 1.4688x; 1.4688x over previous
//
#include <hip/hip_runtime.h>
#include <math.h>

#define LSZ 128
#define NCH 8
#define NLAY 16

__device__ __forceinline__ float4 f4add(float4 a, float4 b) {
    return make_float4(a.x + b.x, a.y + b.y, a.z + b.z, a.w + b.w);
}
__device__ __forceinline__ float4 f4fma(float s, float4 a, float4 acc) {
    return make_float4(fmaf(s, a.x, acc.x), fmaf(s, a.y, acc.y),
                       fmaf(s, a.z, acc.z), fmaf(s, a.w, acc.w));
}
__device__ __forceinline__ float4 f4scale(float s, float4 a) {
    return make_float4(s * a.x, s * a.y, s * a.z, s * a.w);
}
// CELU(y) = max(y,0) + exp(min(y,0)) - 1 ; exact for y>=0, ~1e-7 abs err for y<0.
__device__ __forceinline__ float celu1(float y) {
    return fmaxf(y, 0.f) + (__expf(fminf(y, 0.f)) - 1.f);
}
// wave-uniform float -> SGPR
__device__ __forceinline__ float uni(float v) {
    return __uint_as_float(__builtin_amdgcn_readfirstlane(__float_as_uint(v)));
}

// One block per (batch, channel) plane. 512 threads: 16 row-strips x 32 col-groups.
// Each thread owns 8 rows x 4 cols. Plane in LDS (64 KB), updated in place.
// Own rows carried in registers (cr[4..11]); halo rows + L/R columns re-read.
// waves_per_eu(4): VGPR cap 128 == the 2-blocks/CU tier (LDS caps at 2 anyway);
// goal is cr[] fully in arch VGPRs + prefetch headroom (no AGPR tax, no scratch).
// m-loop is software-pipelined: L/R for m+1 issued while computing m.
__global__ __launch_bounds__(512)
__attribute__((amdgpu_waves_per_eu(4)))
void plane_kernel(const float* __restrict__ nrm,   // (256,128,3)
                  const float* __restrict__ W,     // (16,8,5)
                  float* __restrict__ ws)          // (2048,) per-block sums
{
    __shared__ float x[LSZ * LSZ];     // 65536 B
    __shared__ float nsm[LSZ * 3];
    __shared__ float wsm[NLAY * 5];
    __shared__ float red[8];

    const int bid = blockIdx.x;
    const int b   = bid >> 3;
    const int c   = bid & 7;
    const int tid = threadIdx.x;

    if (tid < LSZ * 3) nsm[tid] = nrm[b * (LSZ * 3) + tid];
    if (tid < NLAY * 5) {
        int l = tid / 5, d = tid % 5;
        wsm[tid] = W[l * (NCH * 5) + c * 5 + d];
    }
    __syncthreads();

    const int jg = tid & 31;        // col group
    const int is = tid >> 5;        // row strip
    const int j0 = jg * 4;
    const int i0 = is * 8;

    float4 cr[16];   // rows i0-4 .. i0+11 (wrapped); cr[m] doubles as out stash

    // ---- init: g[i][j] = dot3(n[i], n[j]), zero diagonal ----
    {
        float nj0x = nsm[(j0 + 0) * 3 + 0], nj0y = nsm[(j0 + 0) * 3 + 1], nj0z = nsm[(j0 + 0) * 3 + 2];
        float nj1x = nsm[(j0 + 1) * 3 + 0], nj1y = nsm[(j0 + 1) * 3 + 1], nj1z = nsm[(j0 + 1) * 3 + 2];
        float nj2x = nsm[(j0 + 2) * 3 + 0], nj2y = nsm[(j0 + 2) * 3 + 1], nj2z = nsm[(j0 + 2) * 3 + 2];
        float nj3x = nsm[(j0 + 3) * 3 + 0], nj3y = nsm[(j0 + 3) * 3 + 1], nj3z = nsm[(j0 + 3) * 3 + 2];
#pragma unroll
        for (int k = 0; k < 8; ++k) {
            int r = i0 + k;
            float n0 = nsm[r * 3 + 0], n1 = nsm[r * 3 + 1], n2 = nsm[r * 3 + 2];
            float g0 = n0 * nj0x + n1 * nj0y + n2 * nj0z;
            float g1 = n0 * nj1x + n1 * nj1y + n2 * nj1z;
            float g2 = n0 * nj2x + n1 * nj2y + n2 * nj2z;
            float g3 = n0 * nj3x + n1 * nj3y + n2 * nj3z;
            if (r == j0 + 0) g0 = 0.f;
            if (r == j0 + 1) g1 = 0.f;
            if (r == j0 + 2) g2 = 0.f;
            if (r == j0 + 3) g3 = 0.f;
            float4 v = make_float4(g0, g1, g2, g3);
            *(float4*)&x[r * LSZ + j0] = v;
            cr[4 + k] = v;
        }
    }
    __syncthreads();

    // wrap-free base pointers (each 4-row halo group is contiguous even across
    // the wrap, since strips are 8-aligned). All per-row offsets are k*LSZ ->
    // ds_read immediate offsets, no per-layer address math.
    const float* pT = x + ((i0 - 4) & (LSZ - 1)) * LSZ + j0;   // top halo rows
    const float* pB = x + ((i0 + 8) & (LSZ - 1)) * LSZ + j0;   // bottom halo rows
    const float* pL = x + i0 * LSZ + ((j0 - 4) & (LSZ - 1));   // left cols, own rows
    const float* pR = x + i0 * LSZ + ((j0 + 4) & (LSZ - 1));   // right cols, own rows
    float*       pO = x + i0 * LSZ + j0;                       // own rows

#pragma unroll 1
    for (int l = 0; l < NLAY; ++l) {
        const float w0 = uni(wsm[l * 5 + 0]);
        const float w1 = uni(wsm[l * 5 + 1]);
        const float w2 = uni(wsm[l * 5 + 2]);
        const float w3 = uni(wsm[l * 5 + 3]);
        const float w4 = uni(wsm[l * 5 + 4]);

        // halo rows (own rows already live in cr[4..11])
#pragma unroll
        for (int k = 0; k < 4; ++k) {
            cr[k]      = *(const float4*)&pT[k * LSZ];
            cr[12 + k] = *(const float4*)&pB[k * LSZ];
        }

        // software-pipelined m-loop: issue L/R for m+1 before computing m
        float4 Lc = *(const float4*)&pL[0];
        float4 Rc = *(const float4*)&pR[0];
#pragma unroll
        for (int m = 0; m < 8; ++m) {
            float4 Ln, Rn;
            if (m < 7) {
                Ln = *(const float4*)&pL[(m + 1) * LSZ];
                Rn = *(const float4*)&pR[(m + 1) * LSZ];
            }
            const float4 C = cr[m + 4];

            float4 h1 = make_float4(Lc.w + C.y, C.x + C.z, C.y + C.w, C.z + Rc.x);
            float4 h2 = make_float4(Lc.z + C.z, Lc.w + C.w, C.x + Rc.x, C.y + Rc.y);
            float4 h3 = make_float4(Lc.y + C.w, Lc.z + Rc.x, Lc.w + Rc.y, C.x + Rc.z);
            float4 h4 = f4add(Lc, Rc);

            float4 y = f4scale(w0, C);
            y = f4fma(w1, f4add(h1, f4add(cr[m + 3], cr[m + 5])), y);
            y = f4fma(w2, f4add(h2, f4add(cr[m + 2], cr[m + 6])), y);
            y = f4fma(w3, f4add(h3, f4add(cr[m + 1], cr[m + 7])), y);
            y = f4fma(w4, f4add(h4, f4add(cr[m + 0], cr[m + 8])), y);

            float4 res;
            res.x = C.x + celu1(y.x);
            res.y = C.y + celu1(y.y);
            res.z = C.z + celu1(y.z);
            res.w = C.w + celu1(y.w);
            cr[m] = res;                       // stash (cr[m] dead after this m)

            Lc = Ln; Rc = Rn;
        }
        __syncthreads();
#pragma unroll
        for (int m = 0; m < 8; ++m)
            *(float4*)&pO[m * LSZ] = cr[m];
        __syncthreads();

        // carry results into the own-row slots for the next layer
#pragma unroll
        for (int k = 7; k >= 0; --k)
            cr[4 + k] = cr[k];
    }

    // ---- per-block sum of final plane (results live in cr[4..11]) ----
    float local = 0.f;
#pragma unroll
    for (int m = 4; m < 12; ++m)
        local += cr[m].x + cr[m].y + cr[m].z + cr[m].w;

#pragma unroll
    for (int off = 32; off > 0; off >>= 1)
        local += __shfl_down(local, off, 64);

    const int wave = tid >> 6;
    if ((tid & 63) == 0) red[wave] = local;
    __syncthreads();
    if (tid == 0) {
        float s = 0.f;
#pragma unroll
        for (int w = 0; w < 8; ++w) s += red[w];
        ws[bid] = s;
    }
}

__global__ void finish_kernel(const float* __restrict__ ws, float* __restrict__ out) {
    int b = threadIdx.x;
    float s = 0.f;
#pragma unroll
    for (int c = 0; c < NCH; ++c) s += ws[b * NCH + c];
    out[b] = expf(-s / (8.0f * 128.0f * 128.0f));
}

extern "C" void kernel_launch(void* const* d_in, const int* in_sizes, int n_in,
                              void* d_out, int out_size, void* d_ws, size_t ws_size,
                              hipStream_t stream) {
    const float* nrm = (const float*)d_in[0];   // (256,128,3) f32
    const float* W   = (const float*)d_in[1];   // (16,8,5) f32
    float* out = (float*)d_out;                 // (256,) f32
    float* ws  = (float*)d_ws;                  // >= 2048 f32 scratch

    plane_kernel<<<dim3(256 * NCH), dim3(512), 0, stream>>>(nrm, W, ws);
    finish_kernel<<<dim3(1), dim3(256), 0, stream>>>(ws, out);
}

// Round 7
// 309.870 us; speedup vs baseline: 2.3359x; 1.5904x over previous
//
#include <hip/hip_runtime.h>
#include <math.h>

#define LSZ 128
#define NCH 8
#define NLAY 16

// clang ext_vector: true vector ops -> backend can select v_pk_{add,mul,fma}_f32
// (CDNA packed FP32, 2 f32 per VALU instr). The old per-component make_float4
// helpers forced scalar v_add_f32 codegen.
typedef float f4 __attribute__((ext_vector_type(4)));

// CELU(y) = max(y,0) + exp(min(y,0)) - 1 ; exact for y>=0, ~1e-7 abs err for y<0.
__device__ __forceinline__ float celu1(float y) {
    return fmaxf(y, 0.f) + (__expf(fminf(y, 0.f)) - 1.f);
}
// wave-uniform float -> SGPR
__device__ __forceinline__ float uni(float v) {
    return __uint_as_float(__builtin_amdgcn_readfirstlane(__float_as_uint(v)));
}

// One block per (batch, channel) plane. 512 threads: 16 row-strips x 32 col-groups.
// Each thread owns 8 rows x 4 cols. Plane in LDS (64 KB), updated in place.
// Own rows carried in registers (cr[4..11]); halo rows + L/R columns re-read.
// m-loop software-pipelined (L/R prefetch). Inner math in ext_vector f4 ops.
__global__ __launch_bounds__(512)
void plane_kernel(const float* __restrict__ nrm,   // (256,128,3)
                  const float* __restrict__ W,     // (16,8,5)
                  float* __restrict__ ws)          // (2048,) per-block sums
{
    __shared__ float x[LSZ * LSZ];     // 65536 B
    __shared__ float nsm[LSZ * 3];
    __shared__ float wsm[NLAY * 5];
    __shared__ float red[8];

    const int bid = blockIdx.x;
    const int b   = bid >> 3;
    const int c   = bid & 7;
    const int tid = threadIdx.x;

    if (tid < LSZ * 3) nsm[tid] = nrm[b * (LSZ * 3) + tid];
    if (tid < NLAY * 5) {
        int l = tid / 5, d = tid % 5;
        wsm[tid] = W[l * (NCH * 5) + c * 5 + d];
    }
    __syncthreads();

    const int jg = tid & 31;        // col group
    const int is = tid >> 5;        // row strip
    const int j0 = jg * 4;
    const int i0 = is * 8;

    f4 cr[16];   // rows i0-4 .. i0+11 (wrapped); cr[m] doubles as out stash

    // ---- init: g[i][j] = dot3(n[i], n[j]), zero diagonal ----
    {
        float nj0x = nsm[(j0 + 0) * 3 + 0], nj0y = nsm[(j0 + 0) * 3 + 1], nj0z = nsm[(j0 + 0) * 3 + 2];
        float nj1x = nsm[(j0 + 1) * 3 + 0], nj1y = nsm[(j0 + 1) * 3 + 1], nj1z = nsm[(j0 + 1) * 3 + 2];
        float nj2x = nsm[(j0 + 2) * 3 + 0], nj2y = nsm[(j0 + 2) * 3 + 1], nj2z = nsm[(j0 + 2) * 3 + 2];
        float nj3x = nsm[(j0 + 3) * 3 + 0], nj3y = nsm[(j0 + 3) * 3 + 1], nj3z = nsm[(j0 + 3) * 3 + 2];
#pragma unroll
        for (int k = 0; k < 8; ++k) {
            int r = i0 + k;
            float n0 = nsm[r * 3 + 0], n1 = nsm[r * 3 + 1], n2 = nsm[r * 3 + 2];
            float g0 = n0 * nj0x + n1 * nj0y + n2 * nj0z;
            float g1 = n0 * nj1x + n1 * nj1y + n2 * nj1z;
            float g2 = n0 * nj2x + n1 * nj2y + n2 * nj2z;
            float g3 = n0 * nj3x + n1 * nj3y + n2 * nj3z;
            if (r == j0 + 0) g0 = 0.f;
            if (r == j0 + 1) g1 = 0.f;
            if (r == j0 + 2) g2 = 0.f;
            if (r == j0 + 3) g3 = 0.f;
            f4 v = (f4){g0, g1, g2, g3};
            *(f4*)&x[r * LSZ + j0] = v;
            cr[4 + k] = v;
        }
    }
    __syncthreads();

    // wrap-free base pointers (4-row halo groups are contiguous across wrap
    // since strips are 8-aligned). Row offsets k*LSZ -> ds_read immediates.
    const float* pT = x + ((i0 - 4) & (LSZ - 1)) * LSZ + j0;   // top halo rows
    const float* pB = x + ((i0 + 8) & (LSZ - 1)) * LSZ + j0;   // bottom halo rows
    const float* pL = x + i0 * LSZ + ((j0 - 4) & (LSZ - 1));   // left cols, own rows
    const float* pR = x + i0 * LSZ + ((j0 + 4) & (LSZ - 1));   // right cols, own rows
    float*       pO = x + i0 * LSZ + j0;                       // own rows

#pragma unroll 1
    for (int l = 0; l < NLAY; ++l) {
        const float w0 = uni(wsm[l * 5 + 0]);
        const float w1 = uni(wsm[l * 5 + 1]);
        const float w2 = uni(wsm[l * 5 + 2]);
        const float w3 = uni(wsm[l * 5 + 3]);
        const float w4 = uni(wsm[l * 5 + 4]);

        // halo rows (own rows already live in cr[4..11])
#pragma unroll
        for (int k = 0; k < 4; ++k) {
            cr[k]      = *(const f4*)&pT[k * LSZ];
            cr[12 + k] = *(const f4*)&pB[k * LSZ];
        }

        // software-pipelined m-loop: issue L/R for m+1 before computing m
        f4 Lc = *(const f4*)&pL[0];
        f4 Rc = *(const f4*)&pR[0];
#pragma unroll
        for (int m = 0; m < 8; ++m) {
            f4 Ln, Rn;
            if (m < 7) {
                Ln = *(const f4*)&pL[(m + 1) * LSZ];
                Rn = *(const f4*)&pR[(m + 1) * LSZ];
            }
            const f4 C = cr[m + 4];

            // horizontal shifted-pair taps (scalar component gathers; the
            // adds below on whole vectors go to v_pk_* ops)
            f4 h1 = (f4){Lc.w + C.y, C.x + C.z, C.y + C.w, C.z + Rc.x};
            f4 h2 = (f4){Lc.z + C.z, Lc.w + C.w, C.x + Rc.x, C.y + Rc.y};
            f4 h3 = (f4){Lc.y + C.w, Lc.z + Rc.x, Lc.w + Rc.y, C.x + Rc.z};
            f4 h4 = Lc + Rc;

            f4 y = w0 * C
                 + w1 * (h1 + (cr[m + 3] + cr[m + 5]))
                 + w2 * (h2 + (cr[m + 2] + cr[m + 6]))
                 + w3 * (h3 + (cr[m + 1] + cr[m + 7]))
                 + w4 * (h4 + (cr[m + 0] + cr[m + 8]));

            f4 res;
            res.x = C.x + celu1(y.x);
            res.y = C.y + celu1(y.y);
            res.z = C.z + celu1(y.z);
            res.w = C.w + celu1(y.w);
            cr[m] = res;                       // stash (cr[m] dead after this m)

            Lc = Ln; Rc = Rn;
        }
        __syncthreads();
#pragma unroll
        for (int m = 0; m < 8; ++m)
            *(f4*)&pO[m * LSZ] = cr[m];
        __syncthreads();

        // carry results into the own-row slots for the next layer
#pragma unroll
        for (int k = 7; k >= 0; --k)
            cr[4 + k] = cr[k];
    }

    // ---- per-block sum of final plane (results live in cr[4..11]) ----
    float local = 0.f;
#pragma unroll
    for (int m = 4; m < 12; ++m)
        local += cr[m].x + cr[m].y + cr[m].z + cr[m].w;

#pragma unroll
    for (int off = 32; off > 0; off >>= 1)
        local += __shfl_down(local, off, 64);

    const int wave = tid >> 6;
    if ((tid & 63) == 0) red[wave] = local;
    __syncthreads();
    if (tid == 0) {
        float s = 0.f;
#pragma unroll
        for (int w = 0; w < 8; ++w) s += red[w];
        ws[bid] = s;
    }
}

__global__ void finish_kernel(const float* __restrict__ ws, float* __restrict__ out) {
    int b = threadIdx.x;
    float s = 0.f;
#pragma unroll
    for (int c = 0; c < NCH; ++c) s += ws[b * NCH + c];
    out[b] = expf(-s / (8.0f * 128.0f * 128.0f));
}

extern "C" void kernel_launch(void* const* d_in, const int* in_sizes, int n_in,
                              void* d_out, int out_size, void* d_ws, size_t ws_size,
                              hipStream_t stream) {
    const float* nrm = (const float*)d_in[0];   // (256,128,3) f32
    const float* W   = (const float*)d_in[1];   // (16,8,5) f32
    float* out = (float*)d_out;                 // (256,) f32
    float* ws  = (float*)d_ws;                  // >= 2048 f32 scratch

    plane_kernel<<<dim3(256 * NCH), dim3(512), 0, stream>>>(nrm, W, ws);
    finish_kernel<<<dim3(1), dim3(256), 0, stream>>>(ws, out);
}

// Round 8
// 284.964 us; speedup vs baseline: 2.5401x; 1.0874x over previous
//
#include <hip/hip_runtime.h>
#include <math.h>

#define LSZ 128
#define NCH 8
#define NLAY 16
#define LOG2E 1.4426950408889634f
#define LN2   0.6931471805599453f

// clang ext_vector: true vector ops -> backend selects v_pk_{add,mul,fma}_f32.
typedef float f4 __attribute__((ext_vector_type(4)));

// wave-uniform float -> SGPR
__device__ __forceinline__ float uni(float v) {
    return __uint_as_float(__builtin_amdgcn_readfirstlane(__float_as_uint(v)));
}

// One block per (batch, channel) plane. 512 threads: 16 row-strips x 32 col-groups.
// Each thread owns 8 rows x 4 cols. Plane in LDS (64 KB), updated in place.
// Own rows live in registers; layer loop unrolled 2x with role-swapped banks
// (own -> buf -> own) so there is no carry-shift. Weights are pre-scaled by
// log2e so the tree yields y' = y*log2e; CELU = fma(max(y',0), ln2, C-1) +
// exp2(min(y',0)) -- exact for y>=0, ~1e-7 abs err for y<0.
// amdgpu_num_vgpr(128): request the full 2-blocks/CU arch-VGPR budget so the
// register bank stays in arch VGPRs (no AGPR copy tax).
__global__ __launch_bounds__(512)
__attribute__((amdgpu_num_vgpr(128)))
void plane_kernel(const float* __restrict__ nrm,   // (256,128,3)
                  const float* __restrict__ W,     // (16,8,5)
                  float* __restrict__ ws)          // (2048,) per-block sums
{
    __shared__ float x[LSZ * LSZ];     // 65536 B
    __shared__ float nsm[LSZ * 3];
    __shared__ float wsm[NLAY * 5];
    __shared__ float red[8];

    const int bid = blockIdx.x;
    const int b   = bid >> 3;
    const int c   = bid & 7;
    const int tid = threadIdx.x;

    if (tid < LSZ * 3) nsm[tid] = nrm[b * (LSZ * 3) + tid];
    if (tid < NLAY * 5) {
        int l = tid / 5, d = tid % 5;
        wsm[tid] = W[l * (NCH * 5) + c * 5 + d] * LOG2E;   // pre-scaled
    }
    __syncthreads();

    const int jg = tid & 31;        // col group
    const int is = tid >> 5;        // row strip
    const int j0 = jg * 4;
    const int i0 = is * 8;

    f4 own[8], buf[8];

    // ---- init: g[i][j] = dot3(n[i], n[j]), zero diagonal ----
    {
        float nj0x = nsm[(j0 + 0) * 3 + 0], nj0y = nsm[(j0 + 0) * 3 + 1], nj0z = nsm[(j0 + 0) * 3 + 2];
        float nj1x = nsm[(j0 + 1) * 3 + 0], nj1y = nsm[(j0 + 1) * 3 + 1], nj1z = nsm[(j0 + 1) * 3 + 2];
        float nj2x = nsm[(j0 + 2) * 3 + 0], nj2y = nsm[(j0 + 2) * 3 + 1], nj2z = nsm[(j0 + 2) * 3 + 2];
        float nj3x = nsm[(j0 + 3) * 3 + 0], nj3y = nsm[(j0 + 3) * 3 + 1], nj3z = nsm[(j0 + 3) * 3 + 2];
#pragma unroll
        for (int k = 0; k < 8; ++k) {
            int r = i0 + k;
            float n0 = nsm[r * 3 + 0], n1 = nsm[r * 3 + 1], n2 = nsm[r * 3 + 2];
            float g0 = n0 * nj0x + n1 * nj0y + n2 * nj0z;
            float g1 = n0 * nj1x + n1 * nj1y + n2 * nj1z;
            float g2 = n0 * nj2x + n1 * nj2y + n2 * nj2z;
            float g3 = n0 * nj3x + n1 * nj3y + n2 * nj3z;
            if (r == j0 + 0) g0 = 0.f;
            if (r == j0 + 1) g1 = 0.f;
            if (r == j0 + 2) g2 = 0.f;
            if (r == j0 + 3) g3 = 0.f;
            f4 v = (f4){g0, g1, g2, g3};
            *(f4*)&x[r * LSZ + j0] = v;
            own[k] = v;
        }
    }
    __syncthreads();

    // wrap-free base pointers (4-row halo groups contiguous across wrap since
    // strips are 8-aligned). Row offsets k*LSZ -> ds_read immediates.
    const float* pT = x + ((i0 - 4) & (LSZ - 1)) * LSZ + j0;   // top halo rows
    const float* pB = x + ((i0 + 8) & (LSZ - 1)) * LSZ + j0;   // bottom halo rows
    const float* pL = x + i0 * LSZ + ((j0 - 4) & (LSZ - 1));   // left cols
    const float* pR = x + i0 * LSZ + ((j0 + 4) & (LSZ - 1));   // right cols
    float*       pO = x + i0 * LSZ + j0;                       // own rows

    auto do_layer = [&](const f4* src, f4* dst, int l) {
        const float w0 = uni(wsm[l * 5 + 0]);
        const float w1 = uni(wsm[l * 5 + 1]);
        const float w2 = uni(wsm[l * 5 + 2]);
        const float w3 = uni(wsm[l * 5 + 3]);
        const float w4 = uni(wsm[l * 5 + 4]);

        f4 t[4], bo[4];
#pragma unroll
        for (int k = 0; k < 4; ++k) {
            t[k]  = *(const f4*)&pT[k * LSZ];
            bo[k] = *(const f4*)&pB[k * LSZ];
        }

        // VV(k): vertical stack rows i0-4+k, k = 0..15
#define VV(k) ((k) < 4 ? t[(k)] : (k) < 12 ? src[(k) - 4] : bo[(k) - 12])

        f4 Lc = *(const f4*)&pL[0];
        f4 Rc = *(const f4*)&pR[0];
#pragma unroll
        for (int m = 0; m < 8; ++m) {
            f4 Ln, Rn;
            if (m < 7) {
                Ln = *(const f4*)&pL[(m + 1) * LSZ];
                Rn = *(const f4*)&pR[(m + 1) * LSZ];
            }
            const f4 C = src[m];

            // horizontal shifted-pair taps (scalar gathers); vector adds -> pk
            f4 h1 = (f4){Lc.w + C.y, C.x + C.z, C.y + C.w, C.z + Rc.x};
            f4 h2 = (f4){Lc.z + C.z, Lc.w + C.w, C.x + Rc.x, C.y + Rc.y};
            f4 h3 = (f4){Lc.y + C.w, Lc.z + Rc.x, Lc.w + Rc.y, C.x + Rc.z};
            f4 h4 = Lc + Rc;

            // y' = y * log2e (weights pre-scaled)
            f4 y = w0 * C
                 + w1 * (h1 + (VV(m + 3) + VV(m + 5)))
                 + w2 * (h2 + (VV(m + 2) + VV(m + 6)))
                 + w3 * (h3 + (VV(m + 1) + VV(m + 7)))
                 + w4 * (h4 + (VV(m + 0) + VV(m + 8)));

            f4 Cm1 = C - 1.0f;
            f4 res;
            res.x = fmaf(fmaxf(y.x, 0.f), LN2, Cm1.x) + __builtin_amdgcn_exp2f(fminf(y.x, 0.f));
            res.y = fmaf(fmaxf(y.y, 0.f), LN2, Cm1.y) + __builtin_amdgcn_exp2f(fminf(y.y, 0.f));
            res.z = fmaf(fmaxf(y.z, 0.f), LN2, Cm1.z) + __builtin_amdgcn_exp2f(fminf(y.z, 0.f));
            res.w = fmaf(fmaxf(y.w, 0.f), LN2, Cm1.w) + __builtin_amdgcn_exp2f(fminf(y.w, 0.f));
            dst[m] = res;

            Lc = Ln; Rc = Rn;
        }
#undef VV
        __syncthreads();
#pragma unroll
        for (int m = 0; m < 8; ++m)
            *(f4*)&pO[m * LSZ] = dst[m];
        __syncthreads();
    };

#pragma unroll 1
    for (int l = 0; l < NLAY; l += 2) {
        do_layer(own, buf, l);
        do_layer(buf, own, l + 1);
    }

    // ---- per-block sum of final plane (results in own[0..7]) ----
    float local = 0.f;
#pragma unroll
    for (int m = 0; m < 8; ++m)
        local += own[m].x + own[m].y + own[m].z + own[m].w;

#pragma unroll
    for (int off = 32; off > 0; off >>= 1)
        local += __shfl_down(local, off, 64);

    const int wave = tid >> 6;
    if ((tid & 63) == 0) red[wave] = local;
    __syncthreads();
    if (tid == 0) {
        float s = 0.f;
#pragma unroll
        for (int w = 0; w < 8; ++w) s += red[w];
        ws[bid] = s;
    }
}

__global__ void finish_kernel(const float* __restrict__ ws, float* __restrict__ out) {
    int b = threadIdx.x;
    float s = 0.f;
#pragma unroll
    for (int c = 0; c < NCH; ++c) s += ws[b * NCH + c];
    out[b] = expf(-s / (8.0f * 128.0f * 128.0f));
}

extern "C" void kernel_launch(void* const* d_in, const int* in_sizes, int n_in,
                              void* d_out, int out_size, void* d_ws, size_t ws_size,
                              hipStream_t stream) {
    const float* nrm = (const float*)d_in[0];   // (256,128,3) f32
    const float* W   = (const float*)d_in[1];   // (16,8,5) f32
    float* out = (float*)d_out;                 // (256,) f32
    float* ws  = (float*)d_ws;                  // >= 2048 f32 scratch

    plane_kernel<<<dim3(256 * NCH), dim3(512), 0, stream>>>(nrm, W, ws);
    finish_kernel<<<dim3(1), dim3(256), 0, stream>>>(ws, out);
}

// Round 9
// 277.236 us; speedup vs baseline: 2.6109x; 1.0279x over previous
//
#include <hip/hip_runtime.h>
#include <math.h>

#define LSZ 128
#define NCH 8
#define NLAY 16
#define LOG2E 1.4426950408889634f
#define LN2   0.6931471805599453f

// clang ext_vector: true vector ops -> backend selects v_pk_{add,mul,fma,max,min}_f32.
typedef float f4 __attribute__((ext_vector_type(4)));
typedef float f2 __attribute__((ext_vector_type(2)));

// wave-uniform float -> SGPR
__device__ __forceinline__ float uni(float v) {
    return __uint_as_float(__builtin_amdgcn_readfirstlane(__float_as_uint(v)));
}

// One block per (batch, channel) plane. 512 threads: 16 row-strips x 32 col-groups.
// Each thread owns 8 rows x 4 cols. Plane in LDS (64 KB), updated in place.
// Layer loop unrolled 2x with role-swapped banks (own <-> buf), weights
// pre-scaled by log2e; CELU = fma(max(y',0), ln2, C-1) + exp2(min(y',0)).
// All CELU tail math is whole-vector (pk-f32 lowering); only exp2 is scalar.
__global__ __launch_bounds__(512)
void plane_kernel(const float* __restrict__ nrm,   // (256,128,3)
                  const float* __restrict__ W,     // (16,8,5)
                  float* __restrict__ ws)          // (2048,) per-block sums
{
    __shared__ float x[LSZ * LSZ];     // 65536 B
    __shared__ float nsm[LSZ * 3];
    __shared__ float wsm[NLAY * 5];
    __shared__ float red[8];

    const int bid = blockIdx.x;
    const int b   = bid >> 3;
    const int c   = bid & 7;
    const int tid = threadIdx.x;

    if (tid < LSZ * 3) nsm[tid] = nrm[b * (LSZ * 3) + tid];
    if (tid < NLAY * 5) {
        int l = tid / 5, d = tid % 5;
        wsm[tid] = W[l * (NCH * 5) + c * 5 + d] * LOG2E;   // pre-scaled
    }
    __syncthreads();

    const int jg = tid & 31;        // col group
    const int is = tid >> 5;        // row strip
    const int j0 = jg * 4;
    const int i0 = is * 8;

    f4 own[8], buf[8];

    // ---- init: g[i][j] = dot3(n[i], n[j]), zero diagonal ----
    {
        float nj0x = nsm[(j0 + 0) * 3 + 0], nj0y = nsm[(j0 + 0) * 3 + 1], nj0z = nsm[(j0 + 0) * 3 + 2];
        float nj1x = nsm[(j0 + 1) * 3 + 0], nj1y = nsm[(j0 + 1) * 3 + 1], nj1z = nsm[(j0 + 1) * 3 + 2];
        float nj2x = nsm[(j0 + 2) * 3 + 0], nj2y = nsm[(j0 + 2) * 3 + 1], nj2z = nsm[(j0 + 2) * 3 + 2];
        float nj3x = nsm[(j0 + 3) * 3 + 0], nj3y = nsm[(j0 + 3) * 3 + 1], nj3z = nsm[(j0 + 3) * 3 + 2];
#pragma unroll
        for (int k = 0; k < 8; ++k) {
            int r = i0 + k;
            float n0 = nsm[r * 3 + 0], n1 = nsm[r * 3 + 1], n2 = nsm[r * 3 + 2];
            float g0 = n0 * nj0x + n1 * nj0y + n2 * nj0z;
            float g1 = n0 * nj1x + n1 * nj1y + n2 * nj1z;
            float g2 = n0 * nj2x + n1 * nj2y + n2 * nj2z;
            float g3 = n0 * nj3x + n1 * nj3y + n2 * nj3z;
            if (r == j0 + 0) g0 = 0.f;
            if (r == j0 + 1) g1 = 0.f;
            if (r == j0 + 2) g2 = 0.f;
            if (r == j0 + 3) g3 = 0.f;
            f4 v = (f4){g0, g1, g2, g3};
            *(f4*)&x[r * LSZ + j0] = v;
            own[k] = v;
        }
    }
    __syncthreads();

    // wrap-free base pointers (4-row halo groups contiguous across wrap since
    // strips are 8-aligned). Row offsets k*LSZ -> ds_read immediates.
    const float* pT = x + ((i0 - 4) & (LSZ - 1)) * LSZ + j0;   // top halo rows
    const float* pB = x + ((i0 + 8) & (LSZ - 1)) * LSZ + j0;   // bottom halo rows
    const float* pL = x + i0 * LSZ + ((j0 - 4) & (LSZ - 1));   // left cols
    const float* pR = x + i0 * LSZ + ((j0 + 4) & (LSZ - 1));   // right cols
    float*       pO = x + i0 * LSZ + j0;                       // own rows

    auto do_layer = [&](const f4* src, f4* dst, int l) {
        const float w0 = uni(wsm[l * 5 + 0]);
        const float w1 = uni(wsm[l * 5 + 1]);
        const float w2 = uni(wsm[l * 5 + 2]);
        const float w3 = uni(wsm[l * 5 + 3]);
        const float w4 = uni(wsm[l * 5 + 4]);

        f4 t[4], bo[4];
#pragma unroll
        for (int k = 0; k < 4; ++k) {
            t[k]  = *(const f4*)&pT[k * LSZ];
            bo[k] = *(const f4*)&pB[k * LSZ];
        }

        // VV(k): vertical stack rows i0-4+k, k = 0..15
#define VV(k) ((k) < 4 ? t[(k)] : (k) < 12 ? src[(k) - 4] : bo[(k) - 12])

        f4 Lc = *(const f4*)&pL[0];
        f4 Rc = *(const f4*)&pR[0];
#pragma unroll
        for (int m = 0; m < 8; ++m) {
            f4 Ln, Rn;
            if (m < 7) {
                Ln = *(const f4*)&pL[(m + 1) * LSZ];
                Rn = *(const f4*)&pR[(m + 1) * LSZ];
            }
            const f4 C = src[m];

            // horizontal shifted-pair taps, written to expose pk-f32 pairs:
            // h1: mid pair {C.x+C.z, C.y+C.w} is one pk_add
            f2 h1m = C.xy + C.zw;
            f4 h1 = (f4){Lc.w + C.y, h1m.x, h1m.y, C.z + Rc.x};
            // h2: both halves are aligned-pair adds
            f2 h2a = Lc.zw + C.xy;
            f2 h2b = C.zw + Rc.xy;
            f4 h2 = (f4){h2a.x, h2a.y, h2b.x, h2b.y};
            // h3: mid pair {L.z+R.x, L.w+R.y} is one pk_add
            f2 h3m = Lc.zw + Rc.xy;
            f4 h3 = (f4){Lc.y + C.w, h3m.x, h3m.y, C.x + Rc.z};
            f4 h4 = Lc + Rc;

            // y' = y * log2e (weights pre-scaled)
            f4 y = w0 * C
                 + w1 * (h1 + (VV(m + 3) + VV(m + 5)))
                 + w2 * (h2 + (VV(m + 2) + VV(m + 6)))
                 + w3 * (h3 + (VV(m + 1) + VV(m + 7)))
                 + w4 * (h4 + (VV(m + 0) + VV(m + 8)));

            // CELU tail, whole-vector (pk) except the 4 exp2
            f4 yp = __builtin_elementwise_max(y, (f4)0.0f);
            f4 yn = __builtin_elementwise_min(y, (f4)0.0f);
            f4 e2;
            e2.x = __builtin_amdgcn_exp2f(yn.x);
            e2.y = __builtin_amdgcn_exp2f(yn.y);
            e2.z = __builtin_amdgcn_exp2f(yn.z);
            e2.w = __builtin_amdgcn_exp2f(yn.w);
            dst[m] = (yp * LN2 + (C - 1.0f)) + e2;

            Lc = Ln; Rc = Rn;
        }
#undef VV
        __syncthreads();
#pragma unroll
        for (int m = 0; m < 8; ++m)
            *(f4*)&pO[m * LSZ] = dst[m];
        __syncthreads();
    };

#pragma unroll 1
    for (int l = 0; l < NLAY; l += 2) {
        do_layer(own, buf, l);
        do_layer(buf, own, l + 1);
    }

    // ---- per-block sum of final plane (results in own[0..7]) ----
    float local = 0.f;
#pragma unroll
    for (int m = 0; m < 8; ++m)
        local += own[m].x + own[m].y + own[m].z + own[m].w;

#pragma unroll
    for (int off = 32; off > 0; off >>= 1)
        local += __shfl_down(local, off, 64);

    const int wave = tid >> 6;
    if ((tid & 63) == 0) red[wave] = local;
    __syncthreads();
    if (tid == 0) {
        float s = 0.f;
#pragma unroll
        for (int w = 0; w < 8; ++w) s += red[w];
        ws[bid] = s;
    }
}

__global__ void finish_kernel(const float* __restrict__ ws, float* __restrict__ out) {
    int b = threadIdx.x;
    float s = 0.f;
#pragma unroll
    for (int c = 0; c < NCH; ++c) s += ws[b * NCH + c];
    out[b] = expf(-s / (8.0f * 128.0f * 128.0f));
}

extern "C" void kernel_launch(void* const* d_in, const int* in_sizes, int n_in,
                              void* d_out, int out_size, void* d_ws, size_t ws_size,
                              hipStream_t stream) {
    const float* nrm = (const float*)d_in[0];   // (256,128,3) f32
    const float* W   = (const float*)d_in[1];   // (16,8,5) f32
    float* out = (float*)d_out;                 // (256,) f32
    float* ws  = (float*)d_ws;                  // >= 2048 f32 scratch

    plane_kernel<<<dim3(256 * NCH), dim3(512), 0, stream>>>(nrm, W, ws);
    finish_kernel<<<dim3(1), dim3(256), 0, stream>>>(ws, out);
}

// Round 10
// 274.015 us; speedup vs baseline: 2.6416x; 1.0118x over previous
//
#include <hip/hip_runtime.h>
#include <math.h>

#define LSZ 128
#define NCH 8
#define NLAY 16
#define LOG2E 1.4426950408889634f
#define LN2   0.6931471805599453f

// clang ext_vector: true vector ops -> backend selects v_pk_{add,mul,fma,max,min}_f32.
typedef float f4 __attribute__((ext_vector_type(4)));
typedef float f2 __attribute__((ext_vector_type(2)));

// wave-uniform float -> SGPR
__device__ __forceinline__ float uni(float v) {
    return __uint_as_float(__builtin_amdgcn_readfirstlane(__float_as_uint(v)));
}

// One block per (batch, channel) plane. 1024 threads: 32 row-strips x 32
// col-groups, each thread 4 rows x 4 cols. TWO LDS planes, ping-pong per
// layer (read A, write B) -> ONE barrier per layer and no write hazard.
// Uniform-shift fold: state stored as x~ where x = x~ - l (the celu "-1"
// accumulates uniformly); stencil contribution of the shift is s*T, folded
// into the tree as an SGPR fma addend. Weights pre-scaled by log2e;
// CELU tail = fma(max(y',0), ln2, x~) + exp2(min(y',0)).
__global__ __launch_bounds__(1024)
void plane_kernel(const float* __restrict__ nrm,   // (256,128,3)
                  const float* __restrict__ W,     // (16,8,5)
                  float* __restrict__ ws)          // (2048,) per-block sums
{
    __shared__ float xa[LSZ * LSZ];    // 65536 B
    __shared__ float xb[LSZ * LSZ];    // 65536 B
    __shared__ float nsm[LSZ * 3];
    __shared__ float wsm[NLAY * 5];
    __shared__ float red[16];

    const int bid = blockIdx.x;
    const int b   = bid >> 3;
    const int c   = bid & 7;
    const int tid = threadIdx.x;

    if (tid < LSZ * 3) nsm[tid] = nrm[b * (LSZ * 3) + tid];
    if (tid < NLAY * 5) {
        int l = tid / 5, d = tid % 5;
        wsm[tid] = W[l * (NCH * 5) + c * 5 + d] * LOG2E;   // pre-scaled
    }
    __syncthreads();

    const int jg = tid & 31;        // col group  -> j0 = 4*jg
    const int is = tid >> 5;        // row strip  -> i0 = 4*is
    const int j0 = jg * 4;
    const int i0 = is * 4;

    f4 own[4];   // this thread's 4 rows (x~ state, carried in registers)

    // ---- init: g[i][j] = dot3(n[i], n[j]), zero diagonal (s_0 = 0) ----
    {
        float nj0x = nsm[(j0 + 0) * 3 + 0], nj0y = nsm[(j0 + 0) * 3 + 1], nj0z = nsm[(j0 + 0) * 3 + 2];
        float nj1x = nsm[(j0 + 1) * 3 + 0], nj1y = nsm[(j0 + 1) * 3 + 1], nj1z = nsm[(j0 + 1) * 3 + 2];
        float nj2x = nsm[(j0 + 2) * 3 + 0], nj2y = nsm[(j0 + 2) * 3 + 1], nj2z = nsm[(j0 + 2) * 3 + 2];
        float nj3x = nsm[(j0 + 3) * 3 + 0], nj3y = nsm[(j0 + 3) * 3 + 1], nj3z = nsm[(j0 + 3) * 3 + 2];
#pragma unroll
        for (int k = 0; k < 4; ++k) {
            int r = i0 + k;
            float n0 = nsm[r * 3 + 0], n1 = nsm[r * 3 + 1], n2 = nsm[r * 3 + 2];
            float g0 = n0 * nj0x + n1 * nj0y + n2 * nj0z;
            float g1 = n0 * nj1x + n1 * nj1y + n2 * nj1z;
            float g2 = n0 * nj2x + n1 * nj2y + n2 * nj2z;
            float g3 = n0 * nj3x + n1 * nj3y + n2 * nj3z;
            if (r == j0 + 0) g0 = 0.f;
            if (r == j0 + 1) g1 = 0.f;
            if (r == j0 + 2) g2 = 0.f;
            if (r == j0 + 3) g3 = 0.f;
            f4 v = (f4){g0, g1, g2, g3};
            *(f4*)&xa[r * LSZ + j0] = v;
            own[k] = v;
        }
    }
    __syncthreads();

    // LDS offsets (elements). 4-row halo groups are whole neighbor strips ->
    // contiguous even across wrap. Row offsets k*LSZ -> ds_read immediates.
    const int oT = ((i0 - 4) & (LSZ - 1)) * LSZ + j0;   // top halo strip
    const int oB = ((i0 + 4) & (LSZ - 1)) * LSZ + j0;   // bottom halo strip
    const int oL = i0 * LSZ + ((j0 - 4) & (LSZ - 1));   // left cols
    const int oR = i0 * LSZ + ((j0 + 4) & (LSZ - 1));   // right cols
    const int oO = i0 * LSZ + j0;                       // own rows

    auto do_layer = [&](const float* src, float* dst, int l) {
        const float w0 = uni(wsm[l * 5 + 0]);
        const float w1 = uni(wsm[l * 5 + 1]);
        const float w2 = uni(wsm[l * 5 + 2]);
        const float w3 = uni(wsm[l * 5 + 3]);
        const float w4 = uni(wsm[l * 5 + 4]);
        // uniform shift: entering layer l, x = x~ - l; stencil(const) = s*T
        const float sT = -(float)l * (w0 + 4.0f * (w1 + w2 + w3 + w4));

        f4 t[4], bo[4], res[4];
#pragma unroll
        for (int k = 0; k < 4; ++k) {
            t[k]  = *(const f4*)&src[oT + k * LSZ];
            bo[k] = *(const f4*)&src[oB + k * LSZ];
        }

        // VV(k): vertical stack rows i0-4+k, k = 0..11
#define VV(k) ((k) < 4 ? t[(k)] : (k) < 8 ? own[(k) - 4] : bo[(k) - 8])

        f4 Lc = *(const f4*)&src[oL];
        f4 Rc = *(const f4*)&src[oR];
#pragma unroll
        for (int m = 0; m < 4; ++m) {
            f4 Ln, Rn;
            if (m < 3) {
                Ln = *(const f4*)&src[oL + (m + 1) * LSZ];
                Rn = *(const f4*)&src[oR + (m + 1) * LSZ];
            }
            const f4 C = own[m];

            // horizontal shifted-pair taps (correct pk pairs; R9's h2 bug fixed)
            f2 h1m = C.xy + C.zw;                      // {C.x+C.z, C.y+C.w}
            f4 h1 = (f4){Lc.w + C.y, h1m.x, h1m.y, C.z + Rc.x};
            f2 h2a = Lc.zw + C.zw;                     // {Lc.z+C.z, Lc.w+C.w}
            f2 h2b = C.xy + Rc.xy;                     // {C.x+Rc.x, C.y+Rc.y}
            f4 h2 = (f4){h2a.x, h2a.y, h2b.x, h2b.y};
            f2 h3m = Lc.zw + Rc.xy;                    // {Lc.z+Rc.x, Lc.w+Rc.y}
            f4 h3 = (f4){Lc.y + C.w, h3m.x, h3m.y, C.x + Rc.z};
            f4 h4 = Lc + Rc;

            // y' = y * log2e (weights pre-scaled); sT folds into the first fma
            f4 y = (w0 * C + sT)
                 + w1 * (h1 + (VV(m + 3) + VV(m + 5)))
                 + w2 * (h2 + (VV(m + 2) + VV(m + 6)))
                 + w3 * (h3 + (VV(m + 1) + VV(m + 7)))
                 + w4 * (h4 + (VV(m + 0) + VV(m + 8)));

            f4 yp = __builtin_elementwise_max(y, (f4)0.0f);
            f4 yn = __builtin_elementwise_min(y, (f4)0.0f);
            f4 e2;
            e2.x = __builtin_amdgcn_exp2f(yn.x);
            e2.y = __builtin_amdgcn_exp2f(yn.y);
            e2.z = __builtin_amdgcn_exp2f(yn.z);
            e2.w = __builtin_amdgcn_exp2f(yn.w);
            f4 r = (yp * LN2 + C) + e2;    // x~_next ("-1" lives in the shift)

            *(f4*)&dst[oO + m * LSZ] = r;  // write immediately (plane B unread)
            res[m] = r;

            Lc = Ln; Rc = Rn;
        }
#undef VV
#pragma unroll
        for (int m = 0; m < 4; ++m) own[m] = res[m];
        __syncthreads();                   // single barrier per layer
    };

#pragma unroll 1
    for (int l = 0; l < NLAY; l += 2) {
        do_layer(xa, xb, l);
        do_layer(xb, xa, l + 1);
    }

    // ---- per-block sum of final plane (x~ in own[0..3]) ----
    float local = 0.f;
#pragma unroll
    for (int m = 0; m < 4; ++m)
        local += own[m].x + own[m].y + own[m].z + own[m].w;

#pragma unroll
    for (int off = 32; off > 0; off >>= 1)
        local += __shfl_down(local, off, 64);

    const int wave = tid >> 6;
    if ((tid & 63) == 0) red[wave] = local;
    __syncthreads();
    if (tid == 0) {
        float s = 0.f;
#pragma unroll
        for (int w = 0; w < 16; ++w) s += red[w];
        ws[bid] = s;
    }
}

__global__ void finish_kernel(const float* __restrict__ ws, float* __restrict__ out) {
    int b = threadIdx.x;
    float s = 0.f;
#pragma unroll
    for (int c = 0; c < NCH; ++c) s += ws[b * NCH + c];
    // x = x~ - 16 after all layers: mean_true = mean(x~) - 16
    out[b] = expf(16.0f - s / (8.0f * 128.0f * 128.0f));
}

extern "C" void kernel_launch(void* const* d_in, const int* in_sizes, int n_in,
                              void* d_out, int out_size, void* d_ws, size_t ws_size,
                              hipStream_t stream) {
    const float* nrm = (const float*)d_in[0];   // (256,128,3) f32
    const float* W   = (const float*)d_in[1];   // (16,8,5) f32
    float* out = (float*)d_out;                 // (256,) f32
    float* ws  = (float*)d_ws;                  // >= 2048 f32 scratch

    plane_kernel<<<dim3(256 * NCH), dim3(1024), 0, stream>>>(nrm, W, ws);
    finish_kernel<<<dim3(1), dim3(256), 0, stream>>>(ws, out);
}